// Round 6
// baseline (711.629 us; speedup 1.0000x reference)
//
#include <hip/hip_runtime.h>
#include <math.h>

#define BB 4
#define NN 1024
#define DIMD 1024
#define HHN 16
#define DHH 64
#define MLPD 4096
#define LLN 2
#define CCD 256
#define BNROWS (BB*NN) // 4096

typedef __attribute__((ext_vector_type(8))) _Float16 h8;
typedef __attribute__((ext_vector_type(4))) _Float16 h4;
typedef __attribute__((ext_vector_type(4))) float f32x4;

#define GLD16(gp, lp) __builtin_amdgcn_global_load_lds( \
    (const __attribute__((address_space(1))) void*)(gp), \
    (__attribute__((address_space(3))) void*)(lp), 16, 0, 0)

// ---------------- silu: f32 -> f16 ----------------
__global__ __launch_bounds__(256) void silu_kernel(const float* __restrict__ in,
                                                   _Float16* __restrict__ out, int n4) {
  int i = blockIdx.x * 256 + threadIdx.x;
  if (i < n4) {
    float4 v = ((const float4*)in)[i];
    h4 o;
    o[0] = (_Float16)(v.x / (1.f + __expf(-v.x)));
    o[1] = (_Float16)(v.y / (1.f + __expf(-v.y)));
    o[2] = (_Float16)(v.z / (1.f + __expf(-v.z)));
    o[3] = (_Float16)(v.w / (1.f + __expf(-v.w)));
    ((h4*)out)[i] = o;
  }
}

// ---------------- transpose + cast: in [K][N] f32 -> out [N][K] f16 ----------------
__global__ __launch_bounds__(256) void transpose_cast(const float* __restrict__ in,
                                                      _Float16* __restrict__ out,
                                                      int K, int N) {
  __shared__ float tile[64][68];
  int bx = blockIdx.x * 64;  // n dim
  int by = blockIdx.y * 64;  // k dim
  int tid = threadIdx.x;
  int r0 = tid >> 4, c4 = (tid & 15) * 4;
  #pragma unroll
  for (int i = 0; i < 4; i++) {
    float4 v = *(const float4*)(in + (size_t)(by + r0 + i * 16) * N + bx + c4);
    *(float4*)&tile[r0 + i * 16][c4] = v;
  }
  __syncthreads();
  #pragma unroll
  for (int i = 0; i < 4; i++) {
    int orow = r0 + i * 16;  // n index within tile
    h4 o;
    #pragma unroll
    for (int j = 0; j < 4; j++) o[j] = (_Float16)tile[c4 + j][orow];
    *(h4*)(out + (size_t)(bx + orow) * K + by + c4) = o;
  }
}

// ---------------- V transpose: qkv [B*N][3072] V-part -> vt [B*H][64][N] ----------------
__global__ __launch_bounds__(256) void v_transpose(const _Float16* __restrict__ qkv,
                                                   _Float16* __restrict__ vt) {
  __shared__ _Float16 t[64][72];
  int n0 = blockIdx.x * 64;
  int bh = blockIdx.y;
  int b = bh >> 4;
  const _Float16* src = qkv + (size_t)b * NN * 3072 + 2048 + (bh & 15) * 64;
  int tid = threadIdx.x;
  int row = tid >> 2, c0 = (tid & 3) * 16;
  *(h8*)&t[row][c0] = *(const h8*)(src + (size_t)(n0 + row) * 3072 + c0);
  *(h8*)&t[row][c0 + 8] = *(const h8*)(src + (size_t)(n0 + row) * 3072 + c0 + 8);
  __syncthreads();
  int d = tid >> 2, ns = (tid & 3) * 16;
  h8 o0, o1;
  #pragma unroll
  for (int j = 0; j < 8; j++) { o0[j] = t[ns + j][d]; o1[j] = t[ns + 8 + j][d]; }
  _Float16* dst = vt + ((size_t)bh * 64 + d) * NN + n0 + ns;
  *(h8*)dst = o0;
  *(h8*)(dst + 8) = o1;
}

// ---------------- GEMM: C[M][Nt] = A[M][K] * Bt[Nt][K]^T (+epilogue) ----------------
// 3-deep counted-vmcnt pipeline (T3+T4): tiles t+1,t+2 stay in flight across
// barriers; only tile t is waited on (vmcnt(2L)). Raw s_barrier (no drain).
// MFMA operands swapped so D is transposed: lane&15 -> row, 4*(lane>>4)+q -> cols.
template <int EPI, int BNT>
__global__ __launch_bounds__(256) void gemm_bt(
    const _Float16* __restrict__ A, const _Float16* __restrict__ Bt,
    int M, int Nt, int K,
    const float* __restrict__ bias,
    _Float16* __restrict__ outh,
    float* __restrict__ xio,
    const _Float16* __restrict__ mmb, const _Float16* __restrict__ mfb, int gchunk) {
  constexpr int NREP = BNT / 32;  // 4 or 2
  __shared__ _Float16 As[3][128 * 32];
  __shared__ _Float16 Bs[3][BNT * 32];
  const int tid = threadIdx.x;
  const int wave = tid >> 6, lane = tid & 63;
  const int brow = blockIdx.x * 128, bcol = blockIdx.y * BNT;
  const int wr = (wave >> 1) * 64, wc = (wave & 1) * (BNT / 2);
  const int r = lane & 15, g = lane >> 4;
  f32x4 acc[4][NREP];
  #pragma unroll
  for (int m = 0; m < 4; m++)
    #pragma unroll
    for (int n = 0; n < NREP; n++) acc[m][n] = (f32x4){0.f, 0.f, 0.f, 0.f};

  const _Float16* gA = A + (size_t)(brow + wave * 32 + (lane >> 2)) * K + (lane & 3) * 8;
  const _Float16* gB = Bt + (size_t)(bcol + wave * (BNT / 4) + (lane >> 2)) * K + (lane & 3) * 8;

  // per-wave loads per stage: L = 3 (BNT=64) or 4 (BNT=128)
  auto STAGE = [&](int slot, int k0) {
    GLD16(gA + k0, &As[slot][wave * 1024]);
    GLD16(gA + k0 + 16 * (size_t)K, &As[slot][wave * 1024 + 512]);
    if (BNT == 128) {
      GLD16(gB + k0, &Bs[slot][wave * 1024]);
      GLD16(gB + k0 + 16 * (size_t)K, &Bs[slot][wave * 1024 + 512]);
    } else {
      GLD16(gB + k0, &Bs[slot][wave * 512]);
    }
  };

  const int NT = K / 32;
  #pragma unroll
  for (int s = 0; s < 3; ++s)
    if (s < NT) STAGE(s, s * 32);

  int cur = 0;
  for (int t = 0; t < NT; ++t) {
    const int rem = NT - 1 - t;  // stages still in flight beyond t
    if constexpr (BNT == 128) {
      if (rem >= 2)      asm volatile("s_waitcnt vmcnt(8)" ::: "memory");
      else if (rem == 1) asm volatile("s_waitcnt vmcnt(4)" ::: "memory");
      else               asm volatile("s_waitcnt vmcnt(0)" ::: "memory");
    } else {
      if (rem >= 2)      asm volatile("s_waitcnt vmcnt(6)" ::: "memory");
      else if (rem == 1) asm volatile("s_waitcnt vmcnt(3)" ::: "memory");
      else               asm volatile("s_waitcnt vmcnt(0)" ::: "memory");
    }
    __builtin_amdgcn_s_barrier();  // all waves' tile-t chunks visible
    h8 af[4], bfr[NREP];
    #pragma unroll
    for (int m = 0; m < 4; m++) af[m] = *(const h8*)(&As[cur][(wr + m * 16 + r) * 32 + g * 8]);
    #pragma unroll
    for (int n = 0; n < NREP; n++) bfr[n] = *(const h8*)(&Bs[cur][(wc + n * 16 + r) * 32 + g * 8]);
    #pragma unroll
    for (int m = 0; m < 4; m++)
      #pragma unroll
      for (int n = 0; n < NREP; n++)
        acc[m][n] = __builtin_amdgcn_mfma_f32_16x16x32_f16(bfr[n], af[m], acc[m][n], 0, 0, 0);
    asm volatile("s_waitcnt lgkmcnt(0)" ::: "memory");  // this wave's ds_reads done
    __builtin_amdgcn_s_barrier();                       // all waves done reading slot
    if (t + 3 < NT) STAGE(cur, (t + 3) * 32);           // refill freed slot
    cur = (cur == 2) ? 0 : cur + 1;
  }

  // Transposed-D epilogue: thread owns rows (.. + r), cols (.. + 4g + 0..3)
  #pragma unroll
  for (int m = 0; m < 4; m++) {
    const int grow = brow + wr + m * 16 + r;
    #pragma unroll
    for (int n = 0; n < NREP; n++) {
      const int gcol = bcol + wc + n * 16 + 4 * g;
      float4 bv4 = bias ? *(const float4*)(bias + gcol) : float4{0.f, 0.f, 0.f, 0.f};
      float v[4] = {acc[m][n][0] + bv4.x, acc[m][n][1] + bv4.y,
                    acc[m][n][2] + bv4.z, acc[m][n][3] + bv4.w};
      if (EPI == 0) {
        h4 o;
        #pragma unroll
        for (int q = 0; q < 4; q++) o[q] = (_Float16)v[q];
        *(h4*)(outh + (size_t)grow * Nt + gcol) = o;
      } else if (EPI == 1) {
        h4 o;
        #pragma unroll
        for (int q = 0; q < 4; q++)
          o[q] = (_Float16)(0.5f * v[q] * (1.f + erff(v[q] * 0.70710678118f)));
        *(h4*)(outh + (size_t)grow * Nt + gcol) = o;
      } else {
        h4 gav = (gcol < CCD)
            ? *(const h4*)(mmb + (size_t)grow * (6 * CCD) + gchunk * CCD + gcol)
            : *(const h4*)(mfb + (size_t)grow * (18 * CCD) + gchunk * (3 * CCD) + (gcol - CCD));
        float4 xv = *(float4*)(xio + (size_t)grow * DIMD + gcol);
        xv.x += (float)gav[0] * v[0];
        xv.y += (float)gav[1] * v[1];
        xv.z += (float)gav[2] * v[2];
        xv.w += (float)gav[3] * v[3];
        *(float4*)(xio + (size_t)grow * DIMD + gcol) = xv;
      }
    }
  }
}

// ---------------- LayerNorm + modulation: h = ln(x)*(1+sc)+sh -> f16 ----------------
__global__ __launch_bounds__(256) void ln_mod(const float* __restrict__ x,
                                              const float* __restrict__ gam,
                                              const float* __restrict__ bet,
                                              const _Float16* __restrict__ mmb,
                                              const _Float16* __restrict__ mfb,
                                              int jsh, int jsc,
                                              _Float16* __restrict__ hout) {
  const int row = blockIdx.x;
  const int tid = threadIdx.x;
  const float* xr = x + (size_t)row * DIMD;
  float4 v = ((const float4*)xr)[tid];
  float s = v.x + v.y + v.z + v.w;
  float sq = v.x * v.x + v.y * v.y + v.z * v.z + v.w * v.w;
  #pragma unroll
  for (int off = 32; off > 0; off >>= 1) {
    s += __shfl_down(s, off);
    sq += __shfl_down(sq, off);
  }
  __shared__ float red[8];
  int wv = tid >> 6, ln = tid & 63;
  if (ln == 0) { red[wv] = s; red[4 + wv] = sq; }
  __syncthreads();
  s = red[0] + red[1] + red[2] + red[3];
  sq = red[4] + red[5] + red[6] + red[7];
  float mean = s * (1.f / DIMD);
  float var = sq * (1.f / DIMD) - mean * mean;
  float rs = rsqrtf(var + 1e-5f);
  int c0 = tid * 4;
  float4 gm = ((const float4*)gam)[tid];
  float4 bt = ((const float4*)bet)[tid];
  float xv[4] = {v.x, v.y, v.z, v.w};
  float gv[4] = {gm.x, gm.y, gm.z, gm.w};
  float bv[4] = {bt.x, bt.y, bt.z, bt.w};
  h4 o;
  #pragma unroll
  for (int i = 0; i < 4; i++) {
    int c = c0 + i;
    float lnv = (xv[i] - mean) * rs * gv[i] + bv[i];
    float shv, scv;
    if (c < CCD) {
      shv = (float)mmb[(size_t)row * (6 * CCD) + jsh * CCD + c];
      scv = (float)mmb[(size_t)row * (6 * CCD) + jsc * CCD + c];
    } else {
      shv = (float)mfb[(size_t)row * (18 * CCD) + jsh * (3 * CCD) + (c - CCD)];
      scv = (float)mfb[(size_t)row * (18 * CCD) + jsc * (3 * CCD) + (c - CCD)];
    }
    o[i] = (_Float16)(lnv * (1.f + scv) + shv);
  }
  *((h4*)(hout + (size_t)row * DIMD + c0)) = o;
}

// ---------------- flash attention (LDS-staged, double-buffered) ----------------
// grid (8, 64): XCD-aware remap -> head = bx*8 + (by&7), qtile = by>>3.
// 256 thr = 4 waves; wave owns 32 q rows (2 x 16-row frags); 64-key tiles.
// K and Vt staged in LDS via global_load_lds with XOR-swizzle (pre-swizzled src).
__global__ __launch_bounds__(256) void attn_kernel(const _Float16* __restrict__ qkv,
                                                   const _Float16* __restrict__ vt,
                                                   _Float16* __restrict__ o) {
  __shared__ _Float16 Ks[2 * 64 * 64];
  __shared__ _Float16 Vs[2 * 64 * 64];
  __shared__ _Float16 Ps[4][32 * 72];
  const int bhg = blockIdx.x * 8 + (blockIdx.y & 7);  // global head 0..63 (same bx -> same XCD)
  const int qt = blockIdx.y >> 3;                     // q tile 0..7
  const int b = bhg >> 4, hh = bhg & 15;
  const int tid = threadIdx.x;
  const int wave = tid >> 6, lane = tid & 63;
  const int r = lane & 15, g = lane >> 4;
  const int RS = 3 * HHN * DHH;  // 3072
  const _Float16* qb = qkv + (size_t)b * NN * RS + hh * DHH;
  const _Float16* kb = qb + HHN * DHH;
  const _Float16* vtb = vt + (size_t)bhg * DHH * NN;
  const int q0 = qt * 128 + wave * 32;

  h8 qf[2][2];
  #pragma unroll
  for (int m = 0; m < 2; m++) {
    qf[m][0] = *(const h8*)(qb + (size_t)(q0 + m * 16 + r) * RS + g * 8);
    qf[m][1] = *(const h8*)(qb + (size_t)(q0 + m * 16 + r) * RS + 32 + g * 8);
  }

  f32x4 oacc[2][4];
  #pragma unroll
  for (int m = 0; m < 2; m++)
    #pragma unroll
    for (int n = 0; n < 4; n++) oacc[m][n] = (f32x4){0.f, 0.f, 0.f, 0.f};
  float mrun[2][4], lrun[2][4];
  #pragma unroll
  for (int m = 0; m < 2; m++)
    #pragma unroll
    for (int q = 0; q < 4; q++) { mrun[m][q] = -1e30f; lrun[m][q] = 0.f; }
  const float scale = 0.125f;  // DH^-0.5
  _Float16* Pw = Ps[wave];

  // stage one 64x64 tile pair (K rows kv x d; Vt rows d x kv), swizzled source
  auto STAGE = [&](int buf, int k0) {
    #pragma unroll
    for (int i = 0; i < 2; i++) {
      int chunk = wave * 2 + i;              // 0..7, wave-uniform
      int blk = chunk * 64 + lane;           // 16B-block index 0..511
      int row = blk >> 3, c16 = blk & 7;
      int sc = ((c16 ^ (row & 7))) * 8;      // pre-swizzled source element offset
      GLD16(kb + (size_t)(k0 + row) * RS + sc, Ks + buf * 4096 + chunk * 512);
      GLD16(vtb + (size_t)row * NN + k0 + sc, Vs + buf * 4096 + chunk * 512);
    }
  };

  STAGE(0, 0);
  int cur = 0;
  for (int kt = 0; kt < NN / 64; ++kt) {
    __syncthreads();  // buf[cur] staged (barrier drains vmcnt); prev compute done
    if (kt + 1 < NN / 64) STAGE(cur ^ 1, (kt + 1) * 64);
    const _Float16* Kb = Ks + cur * 4096;
    const _Float16* Vb = Vs + cur * 4096;
    // QK^T
    f32x4 sfr[2][4];
    #pragma unroll
    for (int m = 0; m < 2; m++)
      #pragma unroll
      for (int n = 0; n < 4; n++) sfr[m][n] = (f32x4){0.f, 0.f, 0.f, 0.f};
    #pragma unroll
    for (int n = 0; n < 4; n++) {
      int row = n * 16 + r, sw = row & 7;
      h8 kf0 = *(const h8*)(Kb + row * 64 + (g ^ sw) * 8);
      h8 kf1 = *(const h8*)(Kb + row * 64 + ((4 + g) ^ sw) * 8);
      #pragma unroll
      for (int m = 0; m < 2; m++) {
        sfr[m][n] = __builtin_amdgcn_mfma_f32_16x16x32_f16(qf[m][0], kf0, sfr[m][n], 0, 0, 0);
        sfr[m][n] = __builtin_amdgcn_mfma_f32_16x16x32_f16(qf[m][1], kf1, sfr[m][n], 0, 0, 0);
      }
    }
    // online softmax per m-frag (rows = 4*g+q, cols over 16 lanes r)
    #pragma unroll
    for (int m = 0; m < 2; m++) {
      float pm[4];
      #pragma unroll
      for (int q = 0; q < 4; q++)
        pm[q] = fmaxf(fmaxf(sfr[m][0][q], sfr[m][1][q]), fmaxf(sfr[m][2][q], sfr[m][3][q])) * scale;
      #pragma unroll
      for (int off = 1; off < 16; off <<= 1)
        #pragma unroll
        for (int q = 0; q < 4; q++) pm[q] = fmaxf(pm[q], __shfl_xor(pm[q], off));
      float fac[4], rsum[4];
      #pragma unroll
      for (int q = 0; q < 4; q++) {
        float mn = fmaxf(mrun[m][q], pm[q]);
        fac[q] = __expf(mrun[m][q] - mn);
        mrun[m][q] = mn;
        rsum[q] = 0.f;
      }
      #pragma unroll
      for (int n = 0; n < 4; n++)
        #pragma unroll
        for (int q = 0; q < 4; q++) {
          float p = __expf(sfr[m][n][q] * scale - mrun[m][q]);
          sfr[m][n][q] = p;
          rsum[q] += p;
        }
      #pragma unroll
      for (int off = 1; off < 16; off <<= 1)
        #pragma unroll
        for (int q = 0; q < 4; q++) rsum[q] += __shfl_xor(rsum[q], off);
      #pragma unroll
      for (int q = 0; q < 4; q++) lrun[m][q] = lrun[m][q] * fac[q] + rsum[q];
      #pragma unroll
      for (int n = 0; n < 4; n++)
        #pragma unroll
        for (int q = 0; q < 4; q++) oacc[m][n][q] *= fac[q];
      // P -> per-wave LDS (D-layout rows)
      #pragma unroll
      for (int n = 0; n < 4; n++)
        #pragma unroll
        for (int q = 0; q < 4; q++)
          Pw[(m * 16 + 4 * g + q) * 72 + n * 16 + r] = (_Float16)sfr[m][n][q];
    }
    // PV (same-wave P readback; V from swizzled LDS)
    h8 pa[2][2];
    #pragma unroll
    for (int m = 0; m < 2; m++) {
      pa[m][0] = *(const h8*)(Pw + (m * 16 + r) * 72 + g * 8);
      pa[m][1] = *(const h8*)(Pw + (m * 16 + r) * 72 + 32 + g * 8);
    }
    #pragma unroll
    for (int nd = 0; nd < 4; nd++) {
      int row = nd * 16 + r, sw = row & 7;
      h8 vf0 = *(const h8*)(Vb + row * 64 + (g ^ sw) * 8);
      h8 vf1 = *(const h8*)(Vb + row * 64 + ((4 + g) ^ sw) * 8);
      #pragma unroll
      for (int m = 0; m < 2; m++) {
        oacc[m][nd] = __builtin_amdgcn_mfma_f32_16x16x32_f16(pa[m][0], vf0, oacc[m][nd], 0, 0, 0);
        oacc[m][nd] = __builtin_amdgcn_mfma_f32_16x16x32_f16(pa[m][1], vf1, oacc[m][nd], 0, 0, 0);
      }
    }
    cur ^= 1;
  }
  #pragma unroll
  for (int m = 0; m < 2; m++)
    #pragma unroll
    for (int nd = 0; nd < 4; nd++)
      #pragma unroll
      for (int q = 0; q < 4; q++) {
        int row = q0 + m * 16 + 4 * g + q;
        int col = hh * DHH + nd * 16 + r;
        o[((size_t)b * NN + row) * DIMD + col] = (_Float16)(oacc[m][nd][q] / lrun[m][q]);
      }
}

// ---------------- launcher ----------------
extern "C" void kernel_launch(void* const* d_in, const int* in_sizes, int n_in,
                              void* d_out, int out_size, void* d_ws, size_t ws_size,
                              hipStream_t stream) {
  (void)in_sizes; (void)n_in; (void)out_size; (void)ws_size;
  const float* mu   = (const float*)d_in[1];
  const float* f_in = (const float*)d_in[2];
  const float* Wqkv = (const float*)d_in[3];
  const float* Wout = (const float*)d_in[4];
  const float* bout = (const float*)d_in[5];
  const float* W1   = (const float*)d_in[6];
  const float* b1   = (const float*)d_in[7];
  const float* W2   = (const float*)d_in[8];
  const float* b2   = (const float*)d_in[9];
  const float* Wmu  = (const float*)d_in[10];
  const float* bmu  = (const float*)d_in[11];
  const float* Wf   = (const float*)d_in[12];
  const float* bfv  = (const float*)d_in[13];
  const float* g1   = (const float*)d_in[14];
  const float* be1  = (const float*)d_in[15];
  const float* g2   = (const float*)d_in[16];
  const float* be2  = (const float*)d_in[17];
  float* xout = (float*)d_out;

  char* ws = (char*)d_ws;
  size_t off = 0;
  auto alloc = [&](size_t elems) -> _Float16* {
    _Float16* p = (_Float16*)(ws + off);
    off += ((elems * 2 + 255) / 256) * 256;
    return p;
  };
  _Float16* wTqkv = alloc((size_t)LLN * 3072 * 1024);
  _Float16* wTout = alloc((size_t)LLN * 1024 * 1024);
  _Float16* wT1   = alloc((size_t)LLN * 4096 * 1024);
  _Float16* wT2   = alloc((size_t)LLN * 1024 * 4096);
  _Float16* wTmu  = alloc((size_t)LLN * 1536 * 256);
  _Float16* wTf   = alloc((size_t)LLN * 4608 * 256);
  _Float16* smu   = alloc((size_t)BNROWS * CCD);
  _Float16* sfb   = alloc((size_t)BNROWS * CCD);
  _Float16* mmb   = alloc((size_t)BNROWS * 6 * CCD);
  _Float16* mfb   = alloc((size_t)BNROWS * 18 * CCD);
  _Float16* hbuf  = alloc((size_t)BNROWS * DIMD);
  _Float16* qkvb  = alloc((size_t)BNROWS * 3 * DIMD);
  _Float16* obuf  = alloc((size_t)BNROWS * DIMD);
  _Float16* m1b   = alloc((size_t)BNROWS * MLPD);
  _Float16* vtb   = alloc((size_t)BNROWS * DIMD);

  // x working copy lives in d_out (updated in place by residual epilogues)
  hipMemcpyAsync(d_out, d_in[0], (size_t)BNROWS * DIMD * sizeof(float),
                 hipMemcpyDeviceToDevice, stream);

  silu_kernel<<<BNROWS * CCD / 4 / 256, 256, 0, stream>>>(mu, smu, BNROWS * CCD / 4);
  silu_kernel<<<BNROWS * CCD / 4 / 256, 256, 0, stream>>>(f_in, sfb, BNROWS * CCD / 4);

  for (int l = 0; l < LLN; l++) {
    transpose_cast<<<dim3(3072 / 64, 1024 / 64), 256, 0, stream>>>(
        Wqkv + (size_t)l * 1024 * 3072, wTqkv + (size_t)l * 3072 * 1024, 1024, 3072);
    transpose_cast<<<dim3(1024 / 64, 1024 / 64), 256, 0, stream>>>(
        Wout + (size_t)l * 1024 * 1024, wTout + (size_t)l * 1024 * 1024, 1024, 1024);
    transpose_cast<<<dim3(4096 / 64, 1024 / 64), 256, 0, stream>>>(
        W1 + (size_t)l * 1024 * 4096, wT1 + (size_t)l * 4096 * 1024, 1024, 4096);
    transpose_cast<<<dim3(1024 / 64, 4096 / 64), 256, 0, stream>>>(
        W2 + (size_t)l * 4096 * 1024, wT2 + (size_t)l * 1024 * 4096, 4096, 1024);
    transpose_cast<<<dim3(1536 / 64, 256 / 64), 256, 0, stream>>>(
        Wmu + (size_t)l * 256 * 1536, wTmu + (size_t)l * 1536 * 256, 256, 1536);
    transpose_cast<<<dim3(4608 / 64, 256 / 64), 256, 0, stream>>>(
        Wf + (size_t)l * 256 * 4608, wTf + (size_t)l * 4608 * 256, 256, 4608);
  }

  for (int l = 0; l < LLN; l++) {
    // modulation GEMMs
    gemm_bt<0, 64><<<dim3(BNROWS / 128, 1536 / 64), 256, 0, stream>>>(
        smu, wTmu + (size_t)l * 1536 * 256, BNROWS, 1536, 256,
        bmu + (size_t)l * 1536, mmb, nullptr, nullptr, nullptr, 0);
    gemm_bt<0, 128><<<dim3(BNROWS / 128, 4608 / 128), 256, 0, stream>>>(
        sfb, wTf + (size_t)l * 4608 * 256, BNROWS, 4608, 256,
        bfv + (size_t)l * 4608, mfb, nullptr, nullptr, nullptr, 0);
    // attention branch
    ln_mod<<<BNROWS, 256, 0, stream>>>(xout, g1 + (size_t)l * DIMD, be1 + (size_t)l * DIMD,
                                       mmb, mfb, 0, 1, hbuf);
    gemm_bt<0, 128><<<dim3(BNROWS / 128, 3072 / 128), 256, 0, stream>>>(
        hbuf, wTqkv + (size_t)l * 3072 * 1024, BNROWS, 3072, 1024,
        nullptr, qkvb, nullptr, nullptr, nullptr, 0);
    v_transpose<<<dim3(NN / 64, BB * HHN), 256, 0, stream>>>(qkvb, vtb);
    attn_kernel<<<dim3(NN / 128, BB * HHN), 256, 0, stream>>>(qkvb, vtb, obuf);
    gemm_bt<2, 64><<<dim3(BNROWS / 128, 1024 / 64), 256, 0, stream>>>(
        obuf, wTout + (size_t)l * 1024 * 1024, BNROWS, 1024, 1024,
        bout + (size_t)l * DIMD, nullptr, xout, mmb, mfb, 2);
    // MLP branch
    ln_mod<<<BNROWS, 256, 0, stream>>>(xout, g2 + (size_t)l * DIMD, be2 + (size_t)l * DIMD,
                                       mmb, mfb, 3, 4, hbuf);
    gemm_bt<1, 128><<<dim3(BNROWS / 128, 4096 / 128), 256, 0, stream>>>(
        hbuf, wT1 + (size_t)l * 4096 * 1024, BNROWS, 4096, 1024,
        b1 + (size_t)l * MLPD, m1b, nullptr, nullptr, nullptr, 0);
    gemm_bt<2, 64><<<dim3(BNROWS / 128, 1024 / 64), 256, 0, stream>>>(
        m1b, wT2 + (size_t)l * 1024 * 4096, BNROWS, 1024, 4096,
        b2 + (size_t)l * DIMD, nullptr, xout, mmb, mfb, 5);
  }
}

// Round 7
// 703.913 us; speedup vs baseline: 1.0110x; 1.0110x over previous
//
#include <hip/hip_runtime.h>
#include <math.h>

#define BB 4
#define NN 1024
#define DIMD 1024
#define HHN 16
#define DHH 64
#define MLPD 4096
#define LLN 2
#define CCD 256
#define BNROWS (BB*NN) // 4096

typedef __attribute__((ext_vector_type(8))) _Float16 h8;
typedef __attribute__((ext_vector_type(4))) _Float16 h4;
typedef __attribute__((ext_vector_type(4))) float f32x4;

#define GLD16(gp, lp) __builtin_amdgcn_global_load_lds( \
    (const __attribute__((address_space(1))) void*)(gp), \
    (__attribute__((address_space(3))) void*)(lp), 16, 0, 0)

// ---------------- silu: f32 -> f16 ----------------
__global__ __launch_bounds__(256) void silu_kernel(const float* __restrict__ in,
                                                   _Float16* __restrict__ out, int n4) {
  int i = blockIdx.x * 256 + threadIdx.x;
  if (i < n4) {
    float4 v = ((const float4*)in)[i];
    h4 o;
    o[0] = (_Float16)(v.x / (1.f + __expf(-v.x)));
    o[1] = (_Float16)(v.y / (1.f + __expf(-v.y)));
    o[2] = (_Float16)(v.z / (1.f + __expf(-v.z)));
    o[3] = (_Float16)(v.w / (1.f + __expf(-v.w)));
    ((h4*)out)[i] = o;
  }
}

// ---------------- transpose + cast: in [K][N] f32 -> out [N][K] f16 ----------------
__global__ __launch_bounds__(256) void transpose_cast(const float* __restrict__ in,
                                                      _Float16* __restrict__ out,
                                                      int K, int N) {
  __shared__ float tile[64][68];
  int bx = blockIdx.x * 64;  // n dim
  int by = blockIdx.y * 64;  // k dim
  int tid = threadIdx.x;
  int r0 = tid >> 4, c4 = (tid & 15) * 4;
  #pragma unroll
  for (int i = 0; i < 4; i++) {
    float4 v = *(const float4*)(in + (size_t)(by + r0 + i * 16) * N + bx + c4);
    *(float4*)&tile[r0 + i * 16][c4] = v;
  }
  __syncthreads();
  #pragma unroll
  for (int i = 0; i < 4; i++) {
    int orow = r0 + i * 16;  // n index within tile
    h4 o;
    #pragma unroll
    for (int j = 0; j < 4; j++) o[j] = (_Float16)tile[c4 + j][orow];
    *(h4*)(out + (size_t)(bx + orow) * K + by + c4) = o;
  }
}

// ---------------- V transpose: qkv [B*N][3072] V-part -> vt [B*H][64][N] ----------------
__global__ __launch_bounds__(256) void v_transpose(const _Float16* __restrict__ qkv,
                                                   _Float16* __restrict__ vt) {
  __shared__ _Float16 t[64][72];
  int n0 = blockIdx.x * 64;
  int bh = blockIdx.y;
  int b = bh >> 4;
  const _Float16* src = qkv + (size_t)b * NN * 3072 + 2048 + (bh & 15) * 64;
  int tid = threadIdx.x;
  int row = tid >> 2, c0 = (tid & 3) * 16;
  *(h8*)&t[row][c0] = *(const h8*)(src + (size_t)(n0 + row) * 3072 + c0);
  *(h8*)&t[row][c0 + 8] = *(const h8*)(src + (size_t)(n0 + row) * 3072 + c0 + 8);
  __syncthreads();
  int d = tid >> 2, ns = (tid & 3) * 16;
  h8 o0, o1;
  #pragma unroll
  for (int j = 0; j < 8; j++) { o0[j] = t[ns + j][d]; o1[j] = t[ns + 8 + j][d]; }
  _Float16* dst = vt + ((size_t)bh * 64 + d) * NN + n0 + ns;
  *(h8*)dst = o0;
  *(h8*)(dst + 8) = o1;
}

// ---------------- GEMM: C[M][Nt] = A[M][K] * Bt[Nt][K]^T (+epilogue) ----------------
// 3-deep counted-vmcnt pipeline + T2 LDS XOR-swizzle (both-sides: pre-swizzled
// global source column, same XOR on the read; LDS dest of global_load_lds stays
// linear). f(row)=(row>>1)&3 spreads 16 lanes over 8 bank-groups (2-way = free).
// MFMA operands swapped so D is transposed: lane&15 -> row, 4*(lane>>4)+q -> cols.
template <int EPI, int BNT>
__global__ __launch_bounds__(256) void gemm_bt(
    const _Float16* __restrict__ A, const _Float16* __restrict__ Bt,
    int M, int Nt, int K,
    const float* __restrict__ bias,
    _Float16* __restrict__ outh,
    float* __restrict__ xio,
    const _Float16* __restrict__ mmb, const _Float16* __restrict__ mfb, int gchunk) {
  constexpr int NREP = BNT / 32;  // 4 or 2
  __shared__ _Float16 As[3][128 * 32];
  __shared__ _Float16 Bs[3][BNT * 32];
  const int tid = threadIdx.x;
  const int wave = tid >> 6, lane = tid & 63;
  const int brow = blockIdx.x * 128, bcol = blockIdx.y * BNT;
  const int wr = (wave >> 1) * 64, wc = (wave & 1) * (BNT / 2);
  const int r = lane & 15, g = lane >> 4;
  f32x4 acc[4][NREP];
  #pragma unroll
  for (int m = 0; m < 4; m++)
    #pragma unroll
    for (int n = 0; n < NREP; n++) acc[m][n] = (f32x4){0.f, 0.f, 0.f, 0.f};

  // T2: source column pre-swizzled with f(row)=(row>>1)&3; dest row within a
  // wave's 1KB chunk is lane>>2, so f = (lane>>3)&3.
  const int scol = ((lane & 3) ^ ((lane >> 3) & 3)) * 8;
  const _Float16* gA = A + (size_t)(brow + wave * 32 + (lane >> 2)) * K + scol;
  const _Float16* gB = Bt + (size_t)(bcol + wave * (BNT / 4) + (lane >> 2)) * K + scol;

  // per-wave loads per stage: L = 3 (BNT=64) or 4 (BNT=128)
  auto STAGE = [&](int slot, int k0) {
    GLD16(gA + k0, &As[slot][wave * 1024]);
    GLD16(gA + k0 + 16 * (size_t)K, &As[slot][wave * 1024 + 512]);
    if (BNT == 128) {
      GLD16(gB + k0, &Bs[slot][wave * 1024]);
      GLD16(gB + k0 + 16 * (size_t)K, &Bs[slot][wave * 1024 + 512]);
    } else {
      GLD16(gB + k0, &Bs[slot][wave * 512]);
    }
  };

  const int NT = K / 32;
  #pragma unroll
  for (int s = 0; s < 3; ++s)
    if (s < NT) STAGE(s, s * 32);

  // read-side swizzled chunk: row bases are multiples of 16 -> f(row)=(r>>1)&3
  const int gg = g ^ ((r >> 1) & 3);

  int cur = 0;
  for (int t = 0; t < NT; ++t) {
    const int rem = NT - 1 - t;  // stages still in flight beyond t
    if constexpr (BNT == 128) {
      if (rem >= 2)      asm volatile("s_waitcnt vmcnt(8)" ::: "memory");
      else if (rem == 1) asm volatile("s_waitcnt vmcnt(4)" ::: "memory");
      else               asm volatile("s_waitcnt vmcnt(0)" ::: "memory");
    } else {
      if (rem >= 2)      asm volatile("s_waitcnt vmcnt(6)" ::: "memory");
      else if (rem == 1) asm volatile("s_waitcnt vmcnt(3)" ::: "memory");
      else               asm volatile("s_waitcnt vmcnt(0)" ::: "memory");
    }
    __builtin_amdgcn_s_barrier();  // all waves' tile-t chunks visible
    h8 af[4], bfr[NREP];
    #pragma unroll
    for (int m = 0; m < 4; m++) af[m] = *(const h8*)(&As[cur][(wr + m * 16 + r) * 32 + gg * 8]);
    #pragma unroll
    for (int n = 0; n < NREP; n++) bfr[n] = *(const h8*)(&Bs[cur][(wc + n * 16 + r) * 32 + gg * 8]);
    #pragma unroll
    for (int m = 0; m < 4; m++)
      #pragma unroll
      for (int n = 0; n < NREP; n++)
        acc[m][n] = __builtin_amdgcn_mfma_f32_16x16x32_f16(bfr[n], af[m], acc[m][n], 0, 0, 0);
    asm volatile("s_waitcnt lgkmcnt(0)" ::: "memory");  // this wave's ds_reads done
    __builtin_amdgcn_s_barrier();                       // all waves done reading slot
    if (t + 3 < NT) STAGE(cur, (t + 3) * 32);           // refill freed slot
    cur = (cur == 2) ? 0 : cur + 1;
  }

  // Transposed-D epilogue: thread owns rows (.. + r), cols (.. + 4g + 0..3)
  #pragma unroll
  for (int m = 0; m < 4; m++) {
    const int grow = brow + wr + m * 16 + r;
    #pragma unroll
    for (int n = 0; n < NREP; n++) {
      const int gcol = bcol + wc + n * 16 + 4 * g;
      float4 bv4 = bias ? *(const float4*)(bias + gcol) : float4{0.f, 0.f, 0.f, 0.f};
      float v[4] = {acc[m][n][0] + bv4.x, acc[m][n][1] + bv4.y,
                    acc[m][n][2] + bv4.z, acc[m][n][3] + bv4.w};
      if (EPI == 0) {
        h4 o;
        #pragma unroll
        for (int q = 0; q < 4; q++) o[q] = (_Float16)v[q];
        *(h4*)(outh + (size_t)grow * Nt + gcol) = o;
      } else if (EPI == 1) {
        h4 o;
        #pragma unroll
        for (int q = 0; q < 4; q++)
          o[q] = (_Float16)(0.5f * v[q] * (1.f + erff(v[q] * 0.70710678118f)));
        *(h4*)(outh + (size_t)grow * Nt + gcol) = o;
      } else {
        h4 gav = (gcol < CCD)
            ? *(const h4*)(mmb + (size_t)grow * (6 * CCD) + gchunk * CCD + gcol)
            : *(const h4*)(mfb + (size_t)grow * (18 * CCD) + gchunk * (3 * CCD) + (gcol - CCD));
        float4 xv = *(float4*)(xio + (size_t)grow * DIMD + gcol);
        xv.x += (float)gav[0] * v[0];
        xv.y += (float)gav[1] * v[1];
        xv.z += (float)gav[2] * v[2];
        xv.w += (float)gav[3] * v[3];
        *(float4*)(xio + (size_t)grow * DIMD + gcol) = xv;
      }
    }
  }
}

// ---------------- LayerNorm + modulation: h = ln(x)*(1+sc)+sh -> f16 ----------------
__global__ __launch_bounds__(256) void ln_mod(const float* __restrict__ x,
                                              const float* __restrict__ gam,
                                              const float* __restrict__ bet,
                                              const _Float16* __restrict__ mmb,
                                              const _Float16* __restrict__ mfb,
                                              int jsh, int jsc,
                                              _Float16* __restrict__ hout) {
  const int row = blockIdx.x;
  const int tid = threadIdx.x;
  const float* xr = x + (size_t)row * DIMD;
  float4 v = ((const float4*)xr)[tid];
  float s = v.x + v.y + v.z + v.w;
  float sq = v.x * v.x + v.y * v.y + v.z * v.z + v.w * v.w;
  #pragma unroll
  for (int off = 32; off > 0; off >>= 1) {
    s += __shfl_down(s, off);
    sq += __shfl_down(sq, off);
  }
  __shared__ float red[8];
  int wv = tid >> 6, ln = tid & 63;
  if (ln == 0) { red[wv] = s; red[4 + wv] = sq; }
  __syncthreads();
  s = red[0] + red[1] + red[2] + red[3];
  sq = red[4] + red[5] + red[6] + red[7];
  float mean = s * (1.f / DIMD);
  float var = sq * (1.f / DIMD) - mean * mean;
  float rs = rsqrtf(var + 1e-5f);
  int c0 = tid * 4;
  float4 gm = ((const float4*)gam)[tid];
  float4 bt = ((const float4*)bet)[tid];
  float xv[4] = {v.x, v.y, v.z, v.w};
  float gv[4] = {gm.x, gm.y, gm.z, gm.w};
  float bv[4] = {bt.x, bt.y, bt.z, bt.w};
  h4 o;
  #pragma unroll
  for (int i = 0; i < 4; i++) {
    int c = c0 + i;
    float lnv = (xv[i] - mean) * rs * gv[i] + bv[i];
    float shv, scv;
    if (c < CCD) {
      shv = (float)mmb[(size_t)row * (6 * CCD) + jsh * CCD + c];
      scv = (float)mmb[(size_t)row * (6 * CCD) + jsc * CCD + c];
    } else {
      shv = (float)mfb[(size_t)row * (18 * CCD) + jsh * (3 * CCD) + (c - CCD)];
      scv = (float)mfb[(size_t)row * (18 * CCD) + jsc * (3 * CCD) + (c - CCD)];
    }
    o[i] = (_Float16)(lnv * (1.f + scv) + shv);
  }
  *((h4*)(hout + (size_t)row * DIMD + c0)) = o;
}

// ---------------- flash attention (LDS-staged, double-buffered) ----------------
// grid (8, 64): XCD-aware remap -> head = bx*8 + (by&7), qtile = by>>3.
// 256 thr = 4 waves; wave owns 32 q rows (2 x 16-row frags); 64-key tiles.
// K and Vt staged in LDS via global_load_lds with XOR-swizzle (pre-swizzled src).
__global__ __launch_bounds__(256) void attn_kernel(const _Float16* __restrict__ qkv,
                                                   const _Float16* __restrict__ vt,
                                                   _Float16* __restrict__ o) {
  __shared__ _Float16 Ks[2 * 64 * 64];
  __shared__ _Float16 Vs[2 * 64 * 64];
  __shared__ _Float16 Ps[4][32 * 72];
  const int bhg = blockIdx.x * 8 + (blockIdx.y & 7);  // global head 0..63 (same bx -> same XCD)
  const int qt = blockIdx.y >> 3;                     // q tile 0..7
  const int b = bhg >> 4, hh = bhg & 15;
  const int tid = threadIdx.x;
  const int wave = tid >> 6, lane = tid & 63;
  const int r = lane & 15, g = lane >> 4;
  const int RS = 3 * HHN * DHH;  // 3072
  const _Float16* qb = qkv + (size_t)b * NN * RS + hh * DHH;
  const _Float16* kb = qb + HHN * DHH;
  const _Float16* vtb = vt + (size_t)bhg * DHH * NN;
  const int q0 = qt * 128 + wave * 32;

  h8 qf[2][2];
  #pragma unroll
  for (int m = 0; m < 2; m++) {
    qf[m][0] = *(const h8*)(qb + (size_t)(q0 + m * 16 + r) * RS + g * 8);
    qf[m][1] = *(const h8*)(qb + (size_t)(q0 + m * 16 + r) * RS + 32 + g * 8);
  }

  f32x4 oacc[2][4];
  #pragma unroll
  for (int m = 0; m < 2; m++)
    #pragma unroll
    for (int n = 0; n < 4; n++) oacc[m][n] = (f32x4){0.f, 0.f, 0.f, 0.f};
  float mrun[2][4], lrun[2][4];
  #pragma unroll
  for (int m = 0; m < 2; m++)
    #pragma unroll
    for (int q = 0; q < 4; q++) { mrun[m][q] = -1e30f; lrun[m][q] = 0.f; }
  const float scale = 0.125f;  // DH^-0.5
  _Float16* Pw = Ps[wave];

  // stage one 64x64 tile pair (K rows kv x d; Vt rows d x kv), swizzled source
  auto STAGE = [&](int buf, int k0) {
    #pragma unroll
    for (int i = 0; i < 2; i++) {
      int chunk = wave * 2 + i;              // 0..7, wave-uniform
      int blk = chunk * 64 + lane;           // 16B-block index 0..511
      int row = blk >> 3, c16 = blk & 7;
      int sc = ((c16 ^ (row & 7))) * 8;      // pre-swizzled source element offset
      GLD16(kb + (size_t)(k0 + row) * RS + sc, Ks + buf * 4096 + chunk * 512);
      GLD16(vtb + (size_t)row * NN + k0 + sc, Vs + buf * 4096 + chunk * 512);
    }
  };

  STAGE(0, 0);
  int cur = 0;
  for (int kt = 0; kt < NN / 64; ++kt) {
    __syncthreads();  // buf[cur] staged (barrier drains vmcnt); prev compute done
    if (kt + 1 < NN / 64) STAGE(cur ^ 1, (kt + 1) * 64);
    const _Float16* Kb = Ks + cur * 4096;
    const _Float16* Vb = Vs + cur * 4096;
    // QK^T
    f32x4 sfr[2][4];
    #pragma unroll
    for (int m = 0; m < 2; m++)
      #pragma unroll
      for (int n = 0; n < 4; n++) sfr[m][n] = (f32x4){0.f, 0.f, 0.f, 0.f};
    #pragma unroll
    for (int n = 0; n < 4; n++) {
      int row = n * 16 + r, sw = row & 7;
      h8 kf0 = *(const h8*)(Kb + row * 64 + (g ^ sw) * 8);
      h8 kf1 = *(const h8*)(Kb + row * 64 + ((4 + g) ^ sw) * 8);
      #pragma unroll
      for (int m = 0; m < 2; m++) {
        sfr[m][n] = __builtin_amdgcn_mfma_f32_16x16x32_f16(qf[m][0], kf0, sfr[m][n], 0, 0, 0);
        sfr[m][n] = __builtin_amdgcn_mfma_f32_16x16x32_f16(qf[m][1], kf1, sfr[m][n], 0, 0, 0);
      }
    }
    // online softmax per m-frag (rows = 4*g+q, cols over 16 lanes r)
    #pragma unroll
    for (int m = 0; m < 2; m++) {
      float pm[4];
      #pragma unroll
      for (int q = 0; q < 4; q++)
        pm[q] = fmaxf(fmaxf(sfr[m][0][q], sfr[m][1][q]), fmaxf(sfr[m][2][q], sfr[m][3][q])) * scale;
      #pragma unroll
      for (int off = 1; off < 16; off <<= 1)
        #pragma unroll
        for (int q = 0; q < 4; q++) pm[q] = fmaxf(pm[q], __shfl_xor(pm[q], off));
      float fac[4], rsum[4];
      #pragma unroll
      for (int q = 0; q < 4; q++) {
        float mn = fmaxf(mrun[m][q], pm[q]);
        fac[q] = __expf(mrun[m][q] - mn);
        mrun[m][q] = mn;
        rsum[q] = 0.f;
      }
      #pragma unroll
      for (int n = 0; n < 4; n++)
        #pragma unroll
        for (int q = 0; q < 4; q++) {
          float p = __expf(sfr[m][n][q] * scale - mrun[m][q]);
          sfr[m][n][q] = p;
          rsum[q] += p;
        }
      #pragma unroll
      for (int off = 1; off < 16; off <<= 1)
        #pragma unroll
        for (int q = 0; q < 4; q++) rsum[q] += __shfl_xor(rsum[q], off);
      #pragma unroll
      for (int q = 0; q < 4; q++) lrun[m][q] = lrun[m][q] * fac[q] + rsum[q];
      #pragma unroll
      for (int n = 0; n < 4; n++)
        #pragma unroll
        for (int q = 0; q < 4; q++) oacc[m][n][q] *= fac[q];
      // P -> per-wave LDS (D-layout rows)
      #pragma unroll
      for (int n = 0; n < 4; n++)
        #pragma unroll
        for (int q = 0; q < 4; q++)
          Pw[(m * 16 + 4 * g + q) * 72 + n * 16 + r] = (_Float16)sfr[m][n][q];
    }
    // PV (same-wave P readback; V from swizzled LDS)
    h8 pa[2][2];
    #pragma unroll
    for (int m = 0; m < 2; m++) {
      pa[m][0] = *(const h8*)(Pw + (m * 16 + r) * 72 + g * 8);
      pa[m][1] = *(const h8*)(Pw + (m * 16 + r) * 72 + 32 + g * 8);
    }
    #pragma unroll
    for (int nd = 0; nd < 4; nd++) {
      int row = nd * 16 + r, sw = row & 7;
      h8 vf0 = *(const h8*)(Vb + row * 64 + (g ^ sw) * 8);
      h8 vf1 = *(const h8*)(Vb + row * 64 + ((4 + g) ^ sw) * 8);
      #pragma unroll
      for (int m = 0; m < 2; m++) {
        oacc[m][nd] = __builtin_amdgcn_mfma_f32_16x16x32_f16(pa[m][0], vf0, oacc[m][nd], 0, 0, 0);
        oacc[m][nd] = __builtin_amdgcn_mfma_f32_16x16x32_f16(pa[m][1], vf1, oacc[m][nd], 0, 0, 0);
      }
    }
    cur ^= 1;
  }
  #pragma unroll
  for (int m = 0; m < 2; m++)
    #pragma unroll
    for (int nd = 0; nd < 4; nd++)
      #pragma unroll
      for (int q = 0; q < 4; q++) {
        int row = q0 + m * 16 + 4 * g + q;
        int col = hh * DHH + nd * 16 + r;
        o[((size_t)b * NN + row) * DIMD + col] = (_Float16)(oacc[m][nd][q] / lrun[m][q]);
      }
}

// ---------------- launcher ----------------
extern "C" void kernel_launch(void* const* d_in, const int* in_sizes, int n_in,
                              void* d_out, int out_size, void* d_ws, size_t ws_size,
                              hipStream_t stream) {
  (void)in_sizes; (void)n_in; (void)out_size; (void)ws_size;
  const float* mu   = (const float*)d_in[1];
  const float* f_in = (const float*)d_in[2];
  const float* Wqkv = (const float*)d_in[3];
  const float* Wout = (const float*)d_in[4];
  const float* bout = (const float*)d_in[5];
  const float* W1   = (const float*)d_in[6];
  const float* b1   = (const float*)d_in[7];
  const float* W2   = (const float*)d_in[8];
  const float* b2   = (const float*)d_in[9];
  const float* Wmu  = (const float*)d_in[10];
  const float* bmu  = (const float*)d_in[11];
  const float* Wf   = (const float*)d_in[12];
  const float* bfv  = (const float*)d_in[13];
  const float* g1   = (const float*)d_in[14];
  const float* be1  = (const float*)d_in[15];
  const float* g2   = (const float*)d_in[16];
  const float* be2  = (const float*)d_in[17];
  float* xout = (float*)d_out;

  char* ws = (char*)d_ws;
  size_t off = 0;
  auto alloc = [&](size_t elems) -> _Float16* {
    _Float16* p = (_Float16*)(ws + off);
    off += ((elems * 2 + 255) / 256) * 256;
    return p;
  };
  _Float16* wTqkv = alloc((size_t)LLN * 3072 * 1024);
  _Float16* wTout = alloc((size_t)LLN * 1024 * 1024);
  _Float16* wT1   = alloc((size_t)LLN * 4096 * 1024);
  _Float16* wT2   = alloc((size_t)LLN * 1024 * 4096);
  _Float16* wTmu  = alloc((size_t)LLN * 1536 * 256);
  _Float16* wTf   = alloc((size_t)LLN * 4608 * 256);
  _Float16* smu   = alloc((size_t)BNROWS * CCD);
  _Float16* sfb   = alloc((size_t)BNROWS * CCD);
  _Float16* mmb   = alloc((size_t)BNROWS * 6 * CCD);
  _Float16* mfb   = alloc((size_t)BNROWS * 18 * CCD);
  _Float16* hbuf  = alloc((size_t)BNROWS * DIMD);
  _Float16* qkvb  = alloc((size_t)BNROWS * 3 * DIMD);
  _Float16* obuf  = alloc((size_t)BNROWS * DIMD);
  _Float16* m1b   = alloc((size_t)BNROWS * MLPD);
  _Float16* vtb   = alloc((size_t)BNROWS * DIMD);

  // x working copy lives in d_out (updated in place by residual epilogues)
  hipMemcpyAsync(d_out, d_in[0], (size_t)BNROWS * DIMD * sizeof(float),
                 hipMemcpyDeviceToDevice, stream);

  silu_kernel<<<BNROWS * CCD / 4 / 256, 256, 0, stream>>>(mu, smu, BNROWS * CCD / 4);
  silu_kernel<<<BNROWS * CCD / 4 / 256, 256, 0, stream>>>(f_in, sfb, BNROWS * CCD / 4);

  for (int l = 0; l < LLN; l++) {
    transpose_cast<<<dim3(3072 / 64, 1024 / 64), 256, 0, stream>>>(
        Wqkv + (size_t)l * 1024 * 3072, wTqkv + (size_t)l * 3072 * 1024, 1024, 3072);
    transpose_cast<<<dim3(1024 / 64, 1024 / 64), 256, 0, stream>>>(
        Wout + (size_t)l * 1024 * 1024, wTout + (size_t)l * 1024 * 1024, 1024, 1024);
    transpose_cast<<<dim3(4096 / 64, 1024 / 64), 256, 0, stream>>>(
        W1 + (size_t)l * 1024 * 4096, wT1 + (size_t)l * 4096 * 1024, 1024, 4096);
    transpose_cast<<<dim3(1024 / 64, 4096 / 64), 256, 0, stream>>>(
        W2 + (size_t)l * 4096 * 1024, wT2 + (size_t)l * 1024 * 4096, 4096, 1024);
    transpose_cast<<<dim3(1536 / 64, 256 / 64), 256, 0, stream>>>(
        Wmu + (size_t)l * 256 * 1536, wTmu + (size_t)l * 1536 * 256, 256, 1536);
    transpose_cast<<<dim3(4608 / 64, 256 / 64), 256, 0, stream>>>(
        Wf + (size_t)l * 256 * 4608, wTf + (size_t)l * 4608 * 256, 256, 4608);
  }

  for (int l = 0; l < LLN; l++) {
    // modulation GEMMs
    gemm_bt<0, 64><<<dim3(BNROWS / 128, 1536 / 64), 256, 0, stream>>>(
        smu, wTmu + (size_t)l * 1536 * 256, BNROWS, 1536, 256,
        bmu + (size_t)l * 1536, mmb, nullptr, nullptr, nullptr, 0);
    gemm_bt<0, 128><<<dim3(BNROWS / 128, 4608 / 128), 256, 0, stream>>>(
        sfb, wTf + (size_t)l * 4608 * 256, BNROWS, 4608, 256,
        bfv + (size_t)l * 4608, mfb, nullptr, nullptr, nullptr, 0);
    // attention branch
    ln_mod<<<BNROWS, 256, 0, stream>>>(xout, g1 + (size_t)l * DIMD, be1 + (size_t)l * DIMD,
                                       mmb, mfb, 0, 1, hbuf);
    gemm_bt<0, 128><<<dim3(BNROWS / 128, 3072 / 128), 256, 0, stream>>>(
        hbuf, wTqkv + (size_t)l * 3072 * 1024, BNROWS, 3072, 1024,
        nullptr, qkvb, nullptr, nullptr, nullptr, 0);
    v_transpose<<<dim3(NN / 64, BB * HHN), 256, 0, stream>>>(qkvb, vtb);
    attn_kernel<<<dim3(NN / 128, BB * HHN), 256, 0, stream>>>(qkvb, vtb, obuf);
    gemm_bt<2, 64><<<dim3(BNROWS / 128, 1024 / 64), 256, 0, stream>>>(
        obuf, wTout + (size_t)l * 1024 * 1024, BNROWS, 1024, 1024,
        bout + (size_t)l * DIMD, nullptr, xout, mmb, mfb, 2);
    // MLP branch
    ln_mod<<<BNROWS, 256, 0, stream>>>(xout, g2 + (size_t)l * DIMD, be2 + (size_t)l * DIMD,
                                       mmb, mfb, 3, 4, hbuf);
    gemm_bt<1, 128><<<dim3(BNROWS / 128, 4096 / 128), 256, 0, stream>>>(
        hbuf, wT1 + (size_t)l * 4096 * 1024, BNROWS, 4096, 1024,
        b1 + (size_t)l * MLPD, m1b, nullptr, nullptr, nullptr, 0);
    gemm_bt<2, 64><<<dim3(BNROWS / 128, 1024 / 64), 256, 0, stream>>>(
        m1b, wT2 + (size_t)l * 1024 * 4096, BNROWS, 1024, 4096,
        b2 + (size_t)l * DIMD, nullptr, xout, mmb, mfb, 5);
  }
}